// Round 1
// baseline (1157.610 us; speedup 1.0000x reference)
//
#include <hip/hip_runtime.h>

#define B_ROWS 500000
#define THRESH 1e-4f

// One wave (64 lanes) processes one row per iteration.
// Phase 1: lanes 0..49 load magnitudes (float4 each: node j = lane/5, quarter m = lane%5),
//          5-lane group max -> per-node signal strength -> ballot -> cutoff.
// Phase 2: lanes 0..40 load float2 of pred/targ (cols 2*lane, 2*lane+1), weighted-square FMA.
__global__ __launch_bounds__(256, 4) void owmse_kernel(
    const float* __restrict__ pred,
    const float* __restrict__ targ,
    const float* __restrict__ inp,
    float* __restrict__ out)
{
    const int lane = threadIdx.x & 63;
    const int wid  = threadIdx.x >> 6;                     // wave in block (0..3)
    const int gwave  = blockIdx.x * (blockDim.x >> 6) + wid;
    const int nwaves = gridDim.x * (blockDim.x >> 6);

    // ---- lane-constant precompute (hoisted out of the row loop) ----
    const int  j        = lane / 5;                        // node 0..9 (lanes 0..49)
    const int  m        = lane - j * 5;                    // float4 index within node
    const bool mag_lane = lane < 50;
    const bool head     = mag_lane && (m == 0);            // lane j*5 holds node max
    const int  mag_off  = j * 40 + m * 4;                  // element offset within row

    const bool mse_lane = lane < 41;
    const int  c0 = 2 * lane;                              // this lane's two columns
    const int  c1 = c0 + 1;
    // spatial mask: first half (0..40): 5 if c%4==0 else 1.
    // second half (41..81): l2=c-41; 5 if (l2%4==0 || l2%4==3) && l2!=40, else 1.
    auto sm = [](int c) -> float {
        if (c >= 82) return 0.0f;
        if (c < 41) return (c % 4 == 0) ? 5.0f : 1.0f;
        int l2 = c - 41;
        if (l2 == 40) return 1.0f;
        int r = l2 & 3;
        return (r == 0 || r == 3) ? 5.0f : 1.0f;
    };
    const float sm0 = sm(c0);
    const float sm1 = sm(c1);
    const int i0 = (c0 < 41) ? c0 : c0 - 41;               // dyn-mask column index
    const int i1 = (c1 < 41) ? c1 : c1 - 41;

    float acc = 0.0f;

    for (int b = gwave; b < B_ROWS; b += nwaves) {
        // ---- phase 1: per-row cutoff from magnitudes ----
        const float* inrow = inp + (size_t)b * 400;
        float4 v = make_float4(0.f, 0.f, 0.f, 0.f);
        if (mag_lane) v = *reinterpret_cast<const float4*>(inrow + mag_off);
        float mx = fmaxf(fmaxf(v.x, v.y), fmaxf(v.z, v.w));
        // group-of-5 max: lane l gets max(v_l..v_{l+4}) valid at l = j*5
        float a = fmaxf(mx, __shfl_down(mx, 1));
        a = fmaxf(a, __shfl_down(a, 2));                   // covers l..l+3
        a = fmaxf(a, __shfl_down(mx, 4));                  // + l+4
        const bool below = head && (a < THRESH);
        const unsigned long long bm = __ballot(below);     // bits at lane j*5
        int cutoff = 1000;                                 // no attenuation
        if (bm != 0ull) cutoff = ((__builtin_ctzll(bm) / 5) + 1) * 4;

        // ---- phase 2: weighted MSE for this row ----
        if (mse_lane) {
            const size_t base = (size_t)b * 82;
            const float2 p = *reinterpret_cast<const float2*>(pred + base + c0);
            const float2 t = *reinterpret_cast<const float2*>(targ + base + c0);
            const float d0 = p.x - t.x;
            const float d1 = p.y - t.y;
            const float w0 = (i0 >= cutoff) ? 0.1f : 1.0f;
            const float w1 = (i1 >= cutoff) ? 0.1f : 1.0f;
            acc = fmaf(sm0 * w0, d0 * d0, acc);
            acc = fmaf(sm1 * w1, d1 * d1, acc);
        }
    }

    // ---- reduction: wave shfl -> LDS -> one atomic per block ----
    for (int off = 32; off > 0; off >>= 1) acc += __shfl_down(acc, off);
    __shared__ float smem[4];
    if (lane == 0) smem[wid] = acc;
    __syncthreads();
    if (threadIdx.x == 0) {
        const float s = smem[0] + smem[1] + smem[2] + smem[3];
        atomicAdd(out, s * (1.0f / (500000.0f * 82.0f)));
    }
}

extern "C" void kernel_launch(void* const* d_in, const int* in_sizes, int n_in,
                              void* d_out, int out_size, void* d_ws, size_t ws_size,
                              hipStream_t stream) {
    const float* pred = (const float*)d_in[0];
    const float* targ = (const float*)d_in[1];
    const float* inp  = (const float*)d_in[2];
    float* out = (float*)d_out;

    // d_out is poisoned 0xAA before every timed launch -> zero it (capture-safe).
    hipMemsetAsync(out, 0, sizeof(float), stream);

    const int threads = 256;
    const int blocks  = 2048;   // 8192 waves -> ~61 rows/wave, saturates 256 CUs
    owmse_kernel<<<blocks, threads, 0, stream>>>(pred, targ, inp, out);
}